// Round 18
// baseline (50.481 us; speedup 1.0000x reference)
//
#include <hip/hip_runtime.h>
#include <hip/hip_bf16.h>

typedef short s16x8 __attribute__((ext_vector_type(8)));
typedef float f32x4 __attribute__((ext_vector_type(4)));
typedef unsigned short us4 __attribute__((ext_vector_type(4)));

static __device__ __forceinline__ unsigned short f2bf(float f) {
  unsigned u = __builtin_bit_cast(unsigned, f);
  u += 0x7FFFu + ((u >> 16) & 1u);
  return (unsigned short)(u >> 16);
}

// 2x f32 -> packed 2x bf16 via intrinsic (emits v_cvt_pk_bf16_f32)
static __device__ __forceinline__ unsigned pk2(float a, float b) {
  __hip_bfloat162 h = __float22bfloat162_rn(make_float2(a, b));
  unsigned r;
  __builtin_memcpy(&r, &h, 4);
  return r;  // a in low 16, b in high 16
}

#if __has_builtin(__builtin_amdgcn_exp2f)
#define EXP2(x) __builtin_amdgcn_exp2f(x)
#else
#define EXP2(x) exp2f(x)
#endif

// q pre-scale: (1/sqrt(64)) * log2(e), so P = exp2(score) == e^{qk/8}
#define QSCALE 0.1803368801111204f

#define MFMA16(a, b, c) __builtin_amdgcn_mfma_f32_16x16x32_bf16((a), (b), (c), 0, 0, 0)

// ---------------------------------------------------------------------------
// Projection (r4 structure, ~92% of stream roofline): out = x @ W^T.
// Frag-major outputs (q pre-scaled by QSCALE).
// ---------------------------------------------------------------------------
__global__ __launch_bounds__(256) void proj_kernel(
    const float* __restrict__ Xq, const float* __restrict__ Xk, const float* __restrict__ Xv,
    const float* __restrict__ Wq, const float* __restrict__ Wk, const float* __restrict__ Wv,
    unsigned short* __restrict__ qf,   // [1024][1024] frag-major
    unsigned short* __restrict__ kf,   // [1024][1024] frag-major
    unsigned short* __restrict__ vfo)  // [256][4096] frag-major
{
  __shared__ __align__(16) unsigned short xs[64][72];
  __shared__ __align__(16) unsigned short ws[64][72];

  const int bid = blockIdx.x;
  const int t = bid >> 8;          // 0=q 1=k 2=v
  const int rb = bid & 255;
  const int b = rb >> 5;
  const int stile = rb & 31;
  const float* X = (t == 0) ? Xq : (t == 1) ? Xk : Xv;
  const float* W = (t == 0) ? Wq : (t == 1) ? Wk : Wv;

  const int tid = threadIdx.x;
  const int wv = tid >> 6;
  const int lane = tid & 63;
  const int j = lane & 15;
  const int g = lane >> 4;

  f32x4 acc[4];
#pragma unroll
  for (int i = 0; i < 4; ++i) acc[i] = {0.f, 0.f, 0.f, 0.f};

  const size_t xrow0 = (size_t)b * 2048 + (size_t)stile * 64;

  for (int kc = 0; kc < 768; kc += 64) {
#pragma unroll
    for (int p = 0; p < 4; ++p) {
      int lin = p * 256 + tid;
      int row = lin >> 4;
      int seg = lin & 15;
      float4 xv = *(const float4*)(X + (xrow0 + row) * 768 + kc + seg * 4);
      uint2 ux; ux.x = pk2(xv.x, xv.y); ux.y = pk2(xv.z, xv.w);
      *(uint2*)&xs[row][seg * 4] = ux;
      float4 wv4 = *(const float4*)(W + (size_t)row * 768 + kc + seg * 4);
      uint2 uw; uw.x = pk2(wv4.x, wv4.y); uw.y = pk2(wv4.z, wv4.w);
      *(uint2*)&ws[row][seg * 4] = uw;
    }
    __syncthreads();
    s16x8 a0 = *(const s16x8*)&xs[wv * 16 + j][g * 8];
    s16x8 a1 = *(const s16x8*)&xs[wv * 16 + j][32 + g * 8];
#pragma unroll
    for (int ct = 0; ct < 4; ++ct) {
      s16x8 b0 = *(const s16x8*)&ws[ct * 16 + j][g * 8];
      s16x8 b1 = *(const s16x8*)&ws[ct * 16 + j][32 + g * 8];
      acc[ct] = MFMA16(a0, b0, acc[ct]);
      acc[ct] = MFMA16(a1, b1, acc[ct]);
    }
    __syncthreads();
  }

  unsigned short* fb = &xs[0][0];
  if (t < 2) {
    const float sc = (t == 0) ? QSCALE : 1.0f;
#pragma unroll
    for (int ct = 0; ct < 4; ++ct) {
      int base16 = wv * 1024 + ((ct >= 2) ? 512 : 0) + (((ct & 1) * 2 + (j >> 3)) * 128) + (j & 7);
#pragma unroll
      for (int r = 0; r < 4; ++r)
        fb[base16 + (g * 4 + r) * 8] = f2bf(acc[ct][r] * sc);
    }
    __syncthreads();
    unsigned short* dst = ((t == 0) ? qf : kf) + ((size_t)b * 128 + stile * 4) * 1024;
#pragma unroll
    for (int p2 = 0; p2 < 2; ++p2) {
      int idx = p2 * 2048 + tid * 8;
      *(s16x8*)(dst + idx) = *(const s16x8*)&fb[idx];
    }
  } else {
#pragma unroll
    for (int ct = 0; ct < 4; ++ct) {
      uint2 uv; uv.x = pk2(acc[ct][0], acc[ct][1]); uv.y = pk2(acc[ct][2], acc[ct][3]);
      *(uint2*)&fb[ct * 1024 + ((wv >= 2) ? 512 : 0) +
                   (((wv & 1) * 2 + (g >> 1)) * 16 + j) * 8 + (g & 1) * 4] = uv;
    }
    __syncthreads();
    unsigned short* gb = vfo + ((size_t)b * 32 + stile) * 4096;
#pragma unroll
    for (int p2 = 0; p2 < 2; ++p2) {
      int idx = p2 * 2048 + tid * 8;
      *(s16x8*)(gb + idx) = *(const s16x8*)&fb[idx];
    }
  }
}

// ---------------------------------------------------------------------------
// Flash attention v13: r15 geometry (32 q-rows/wave, 2-rg reuse, 8-way
// split-K, 512 blocks x 8 waves, 4 waves/SIMD) + T15-style two-tile
// pipeline: P double-buffered in LDS; PV runs one tile behind QK/exp, so
// the P ds_write -> ds_read round-trip never sits on the critical path and
// PV's independent MFMAs fill the QK->exp dependency stalls. Straight-line
// unrolled tile sequence, compile-time buffer indices, fresh per-tile
// transients (no r17-style WAR on reused register arrays).
// ---------------------------------------------------------------------------
__global__ __launch_bounds__(512, 4) void attn_kernel(
    const unsigned short* __restrict__ qf,  // frag-major (QSCALE-scaled)
    const unsigned short* __restrict__ kf,  // frag-major
    const unsigned short* __restrict__ vf,  // frag-major
    float* __restrict__ out)                // [8][2048][64] f32
{
  __shared__ __align__(16) unsigned char raw[73728];  // P x2 (73728B) / comb (69632B) union
  __shared__ float lls[8][32];
  unsigned short* p_lds = (unsigned short*)raw;  // [2 buf][8 waves][2 rg][16 rows][72]
  float* comb = (float*)raw;                     // [8 chunks][32 rows][68]

  const int tid = threadIdx.x;
  const int wv = tid >> 6;   // wave == kv chunk (256 positions)
  const int lane = tid & 63;
  const int j = lane & 15;
  const int g = lane >> 4;

  const int bid0 = blockIdx.x;
  const int swz = (bid0 & 7) * 64 + (bid0 >> 3);  // bijective XCD swizzle (512 = 8*64)
  const int b = swz >> 6;
  const int qt = swz & 63;                        // 32-row q tile

  s16x8 q0[2], q1[2];
#pragma unroll
  for (int rg = 0; rg < 2; ++rg) {
    const unsigned short* qp =
        qf + ((size_t)(b * 128 + qt * 2 + rg)) * 1024 + lane * 8;
    q0[rg] = *(const s16x8*)(qp);
    q1[rg] = *(const s16x8*)(qp + 512);
  }

  f32x4 o[2][4];
#pragma unroll
  for (int rg = 0; rg < 2; ++rg)
#pragma unroll
    for (int i = 0; i < 4; ++i) o[rg][i] = {0.f, 0.f, 0.f, 0.f};
  float l_acc[2] = {0.f, 0.f};

  const unsigned short* kfb = kf + (size_t)b * 131072 + wv * 16384 + lane * 8;
  const unsigned short* vfb = vf + (size_t)b * 131072 + wv * 16384 + lane * 8;
  // per-buffer P row pointers (indexed only by compile-time constants below)
  unsigned short* pw0[2];  // rg0 row in buf 0/1
  unsigned short* pw1[2];  // rg1 row in buf 0/1
  pw0[0] = p_lds + (size_t)((wv * 2 + 0) * 16 + j) * 72;
  pw1[0] = p_lds + (size_t)((wv * 2 + 1) * 16 + j) * 72;
  pw0[1] = pw0[0] + 18432;
  pw1[1] = pw1[0] + 18432;

  // ---- QK + exp2 + P-write for tile kt into buffer buf ----
#define QKEXP(kt, buf)                                                        \
  {                                                                           \
    const unsigned short* kc_ = kfb + (kt) * 4096;                            \
    s16x8 ka[4], kb2[4];                                                      \
    _Pragma("unroll") for (int ct = 0; ct < 4; ++ct) {                        \
      ka[ct] = *(const s16x8*)(kc_ + ct * 1024);                              \
      kb2[ct] = *(const s16x8*)(kc_ + ct * 1024 + 512);                       \
    }                                                                         \
    _Pragma("unroll") for (int rg = 0; rg < 2; ++rg) {                        \
      f32x4 st[4];                                                            \
      _Pragma("unroll") for (int ct = 0; ct < 4; ++ct) {                      \
        f32x4 z = {0.f, 0.f, 0.f, 0.f};                                       \
        z = MFMA16(ka[ct], q0[rg], z);                                        \
        z = MFMA16(kb2[ct], q1[rg], z);                                       \
        st[ct] = z;                                                           \
      }                                                                       \
      unsigned short* pr = (rg ? pw1 : pw0)[buf];                             \
      _Pragma("unroll") for (int ct = 0; ct < 4; ++ct) {                      \
        float p0 = EXP2(st[ct][0]), p1 = EXP2(st[ct][1]);                     \
        float p2 = EXP2(st[ct][2]), p3 = EXP2(st[ct][3]);                     \
        l_acc[rg] += (p0 + p1) + (p2 + p3);                                   \
        uint2 u; u.x = pk2(p0, p1); u.y = pk2(p2, p3);                        \
        *(uint2*)&pr[ct * 16 + g * 4] = u;                                    \
      }                                                                       \
    }                                                                         \
  }

  // ---- PV for tile kt reading P from buffer buf (written a tile ago) ----
#define PVSTEP(kt, buf)                                                       \
  {                                                                           \
    const unsigned short* vc_ = vfb + (kt) * 4096;                            \
    s16x8 va[4], vb2[4];                                                      \
    _Pragma("unroll") for (int dt = 0; dt < 4; ++dt) {                        \
      va[dt] = *(const s16x8*)(vc_ + dt * 1024);                              \
      vb2[dt] = *(const s16x8*)(vc_ + dt * 1024 + 512);                       \
    }                                                                         \
    const unsigned short* r0 = pw0[buf];                                      \
    const unsigned short* r1 = pw1[buf];                                      \
    s16x8 pa0 = *(const s16x8*)&r0[g * 8];                                    \
    s16x8 pa1 = *(const s16x8*)&r0[32 + g * 8];                               \
    s16x8 pb0 = *(const s16x8*)&r1[g * 8];                                    \
    s16x8 pb1 = *(const s16x8*)&r1[32 + g * 8];                               \
    _Pragma("unroll") for (int dt = 0; dt < 4; ++dt) {                        \
      o[0][dt] = MFMA16(pa0, va[dt], o[0][dt]);                               \
      o[0][dt] = MFMA16(pa1, vb2[dt], o[0][dt]);                              \
      o[1][dt] = MFMA16(pb0, va[dt], o[1][dt]);                               \
      o[1][dt] = MFMA16(pb1, vb2[dt], o[1][dt]);                              \
    }                                                                         \
  }

  // ---- pipelined tile sequence: PV lags QK/exp by one tile ----
  QKEXP(0, 0);
  QKEXP(1, 1); PVSTEP(0, 0);
  QKEXP(2, 0); PVSTEP(1, 1);
  QKEXP(3, 1); PVSTEP(2, 0);
  PVSTEP(3, 1);
#undef QKEXP
#undef PVSTEP

  // row-sums of l (lanes j,j+16,j+32,j+48 share q-row j)
#pragma unroll
  for (int rg = 0; rg < 2; ++rg) {
    l_acc[rg] += __shfl_xor(l_acc[rg], 16);
    l_acc[rg] += __shfl_xor(l_acc[rg], 32);
  }

  __syncthreads();  // all waves done with P; raw becomes comb
#pragma unroll
  for (int rg = 0; rg < 2; ++rg) {
#pragma unroll
    for (int dt = 0; dt < 4; ++dt)
#pragma unroll
      for (int r = 0; r < 4; ++r)
        comb[((size_t)wv * 32 + rg * 16 + g * 4 + r) * 68 + dt * 16 + j] = o[rg][dt][r];
    if (g == 0) lls[wv][rg * 16 + j] = l_acc[rg];
  }
  __syncthreads();

  // merge over the 8 kv chunks (pure sum; shift-0) and normalize
#pragma unroll
  for (int it = 0; it < 4; ++it) {
    const int idx = it * 512 + tid;   // 0..2047
    const int row = idx >> 6;         // 0..31 within block tile
    const int d = idx & 63;
    float s = 0.f, lt = 0.f;
#pragma unroll
    for (int cc = 0; cc < 8; ++cc) {
      s += comb[((size_t)cc * 32 + row) * 68 + d];
      lt += lls[cc][row];
    }
    out[(((size_t)b * 2048) + qt * 32 + row) * 64 + d] = s / lt;
  }
}

extern "C" void kernel_launch(void* const* d_in, const int* in_sizes, int n_in,
                              void* d_out, int out_size, void* d_ws, size_t ws_size,
                              hipStream_t stream) {
  const float* query = (const float*)d_in[0];
  const float* key_  = (const float*)d_in[1];
  const float* value = (const float*)d_in[2];
  const float* Wq = (const float*)d_in[3];
  const float* Wk = (const float*)d_in[4];
  const float* Wv = (const float*)d_in[5];

  unsigned short* qfb = (unsigned short*)d_ws;      // 1M shorts
  unsigned short* kfb = qfb + 1048576u;             // 1M shorts
  unsigned short* vfb = qfb + 2u * 1048576u;        // 1M shorts
  float* outp = (float*)d_out;

  hipLaunchKernelGGL(proj_kernel, dim3(768), dim3(256), 0, stream,
                     query, key_, value, Wq, Wk, Wv, qfb, kfb, vfb);
  hipLaunchKernelGGL(attn_kernel, dim3(512), dim3(512), 0, stream,
                     qfb, kfb, vfb, outp);
}

// Round 19
// 43.729 us; speedup vs baseline: 1.1544x; 1.1544x over previous
//
#include <hip/hip_runtime.h>
#include <hip/hip_bf16.h>

typedef short s16x8 __attribute__((ext_vector_type(8)));
typedef float f32x4 __attribute__((ext_vector_type(4)));
typedef unsigned short us4 __attribute__((ext_vector_type(4)));

static __device__ __forceinline__ unsigned short f2bf(float f) {
  unsigned u = __builtin_bit_cast(unsigned, f);
  u += 0x7FFFu + ((u >> 16) & 1u);
  return (unsigned short)(u >> 16);
}

// 2x f32 -> packed 2x bf16 via intrinsic (emits v_cvt_pk_bf16_f32)
static __device__ __forceinline__ unsigned pk2(float a, float b) {
  __hip_bfloat162 h = __float22bfloat162_rn(make_float2(a, b));
  unsigned r;
  __builtin_memcpy(&r, &h, 4);
  return r;  // a in low 16, b in high 16
}

#if __has_builtin(__builtin_amdgcn_exp2f)
#define EXP2(x) __builtin_amdgcn_exp2f(x)
#else
#define EXP2(x) exp2f(x)
#endif

// q pre-scale: (1/sqrt(64)) * log2(e), so P = exp2(score) == e^{qk/8}
#define QSCALE 0.1803368801111204f

#define MFMA16(a, b, c) __builtin_amdgcn_mfma_f32_16x16x32_bf16((a), (b), (c), 0, 0, 0)

// ---------------------------------------------------------------------------
// Projection (r4 structure + T14 register prefetch): out = x @ W^T.
// Next k-chunk's X/W float4s are loaded into registers right after the
// first barrier, hiding global latency under frag-reads + MFMAs + barrier.
// Frag-major outputs (q pre-scaled by QSCALE).
// ---------------------------------------------------------------------------
__global__ __launch_bounds__(256) void proj_kernel(
    const float* __restrict__ Xq, const float* __restrict__ Xk, const float* __restrict__ Xv,
    const float* __restrict__ Wq, const float* __restrict__ Wk, const float* __restrict__ Wv,
    unsigned short* __restrict__ qf,   // [1024][1024] frag-major
    unsigned short* __restrict__ kf,   // [1024][1024] frag-major
    unsigned short* __restrict__ vfo)  // [256][4096] frag-major
{
  __shared__ __align__(16) unsigned short xs[64][72];
  __shared__ __align__(16) unsigned short ws[64][72];

  const int bid = blockIdx.x;
  const int t = bid >> 8;          // 0=q 1=k 2=v
  const int rb = bid & 255;
  const int b = rb >> 5;
  const int stile = rb & 31;
  const float* X = (t == 0) ? Xq : (t == 1) ? Xk : Xv;
  const float* W = (t == 0) ? Wq : (t == 1) ? Wk : Wv;

  const int tid = threadIdx.x;
  const int wv = tid >> 6;
  const int lane = tid & 63;
  const int j = lane & 15;
  const int g = lane >> 4;

  f32x4 acc[4];
#pragma unroll
  for (int i = 0; i < 4; ++i) acc[i] = {0.f, 0.f, 0.f, 0.f};

  const size_t xrow0 = (size_t)b * 2048 + (size_t)stile * 64;

  // prologue: prefetch k-chunk 0 into registers
  float4 xr[4], wr4[4];
#pragma unroll
  for (int p = 0; p < 4; ++p) {
    int lin = p * 256 + tid;
    int row = lin >> 4;
    int seg = lin & 15;
    xr[p] = *(const float4*)(X + (xrow0 + row) * 768 + seg * 4);
    wr4[p] = *(const float4*)(W + (size_t)row * 768 + seg * 4);
  }

  for (int kc = 0; kc < 768; kc += 64) {
    // convert + store current chunk (from prefetched registers)
#pragma unroll
    for (int p = 0; p < 4; ++p) {
      int lin = p * 256 + tid;
      int row = lin >> 4;
      int seg = lin & 15;
      uint2 ux; ux.x = pk2(xr[p].x, xr[p].y); ux.y = pk2(xr[p].z, xr[p].w);
      *(uint2*)&xs[row][seg * 4] = ux;
      uint2 uw; uw.x = pk2(wr4[p].x, wr4[p].y); uw.y = pk2(wr4[p].z, wr4[p].w);
      *(uint2*)&ws[row][seg * 4] = uw;
    }
    __syncthreads();
    // prefetch next chunk — latency hides under frag reads + MFMAs + barrier
    if (kc < 704) {
#pragma unroll
      for (int p = 0; p < 4; ++p) {
        int lin = p * 256 + tid;
        int row = lin >> 4;
        int seg = lin & 15;
        xr[p] = *(const float4*)(X + (xrow0 + row) * 768 + kc + 64 + seg * 4);
        wr4[p] = *(const float4*)(W + (size_t)row * 768 + kc + 64 + seg * 4);
      }
    }
    s16x8 a0 = *(const s16x8*)&xs[wv * 16 + j][g * 8];
    s16x8 a1 = *(const s16x8*)&xs[wv * 16 + j][32 + g * 8];
#pragma unroll
    for (int ct = 0; ct < 4; ++ct) {
      s16x8 b0 = *(const s16x8*)&ws[ct * 16 + j][g * 8];
      s16x8 b1 = *(const s16x8*)&ws[ct * 16 + j][32 + g * 8];
      acc[ct] = MFMA16(a0, b0, acc[ct]);
      acc[ct] = MFMA16(a1, b1, acc[ct]);
    }
    __syncthreads();
  }

  unsigned short* fb = &xs[0][0];
  if (t < 2) {
    const float sc = (t == 0) ? QSCALE : 1.0f;
#pragma unroll
    for (int ct = 0; ct < 4; ++ct) {
      int base16 = wv * 1024 + ((ct >= 2) ? 512 : 0) + (((ct & 1) * 2 + (j >> 3)) * 128) + (j & 7);
#pragma unroll
      for (int r = 0; r < 4; ++r)
        fb[base16 + (g * 4 + r) * 8] = f2bf(acc[ct][r] * sc);
    }
    __syncthreads();
    unsigned short* dst = ((t == 0) ? qf : kf) + ((size_t)b * 128 + stile * 4) * 1024;
#pragma unroll
    for (int p2 = 0; p2 < 2; ++p2) {
      int idx = p2 * 2048 + tid * 8;
      *(s16x8*)(dst + idx) = *(const s16x8*)&fb[idx];
    }
  } else {
#pragma unroll
    for (int ct = 0; ct < 4; ++ct) {
      uint2 uv; uv.x = pk2(acc[ct][0], acc[ct][1]); uv.y = pk2(acc[ct][2], acc[ct][3]);
      *(uint2*)&fb[ct * 1024 + ((wv >= 2) ? 512 : 0) +
                   (((wv & 1) * 2 + (g >> 1)) * 16 + j) * 8 + (g & 1) * 4] = uv;
    }
    __syncthreads();
    unsigned short* gb = vfo + ((size_t)b * 32 + stile) * 4096;
#pragma unroll
    for (int p2 = 0; p2 < 2; ++p2) {
      int idx = p2 * 2048 + tid * 8;
      *(s16x8*)(gb + idx) = *(const s16x8*)&fb[idx];
    }
  }
}

// ---------------------------------------------------------------------------
// Flash attention (r15 verbatim — best measured, 45.4us total): 32 q-rows
// per wave (2 row-groups share every K/V fragment), 8-way split-K, 512
// blocks (batch x 32-row q-tile, XCD swizzle) x 8 waves, 4 waves/SIMD.
// Shift-0 exp2 softmax; pure-sum merge over the 8 chunks.
// ---------------------------------------------------------------------------
__global__ __launch_bounds__(512, 4) void attn_kernel(
    const unsigned short* __restrict__ qf,  // frag-major (QSCALE-scaled)
    const unsigned short* __restrict__ kf,  // frag-major
    const unsigned short* __restrict__ vf,  // frag-major
    float* __restrict__ out)                // [8][2048][64] f32
{
  __shared__ __align__(16) unsigned char raw[69632];  // P (36864B) / comb (69632B) union
  __shared__ float lls[8][32];
  unsigned short* p_lds = (unsigned short*)raw;  // [8 waves][2 rg][16 rows][72]
  float* comb = (float*)raw;                     // [8 chunks][32 rows][68]

  const int tid = threadIdx.x;
  const int wv = tid >> 6;   // wave == kv chunk (256 positions)
  const int lane = tid & 63;
  const int j = lane & 15;
  const int g = lane >> 4;

  const int bid0 = blockIdx.x;
  const int swz = (bid0 & 7) * 64 + (bid0 >> 3);  // bijective XCD swizzle (512 = 8*64)
  const int b = swz >> 6;
  const int qt = swz & 63;                        // 32-row q tile

  s16x8 q0[2], q1[2];
#pragma unroll
  for (int rg = 0; rg < 2; ++rg) {
    const unsigned short* qp =
        qf + ((size_t)(b * 128 + qt * 2 + rg)) * 1024 + lane * 8;
    q0[rg] = *(const s16x8*)(qp);
    q1[rg] = *(const s16x8*)(qp + 512);
  }

  f32x4 o[2][4];
#pragma unroll
  for (int rg = 0; rg < 2; ++rg)
#pragma unroll
    for (int i = 0; i < 4; ++i) o[rg][i] = {0.f, 0.f, 0.f, 0.f};
  float l_acc[2] = {0.f, 0.f};

  const unsigned short* kfb = kf + (size_t)b * 131072 + wv * 16384 + lane * 8;
  const unsigned short* vfb = vf + (size_t)b * 131072 + wv * 16384 + lane * 8;
  unsigned short* myp0 = p_lds + (size_t)((wv * 2 + 0) * 16 + j) * 72;
  unsigned short* myp1 = p_lds + (size_t)((wv * 2 + 1) * 16 + j) * 72;

  for (int kt = 0; kt < 4; ++kt) {
    const unsigned short* kc_ = kfb + kt * 4096;
    s16x8 ka[4], kb2[4];
#pragma unroll
    for (int ct = 0; ct < 4; ++ct) {
      ka[ct] = *(const s16x8*)(kc_ + ct * 1024);
      kb2[ct] = *(const s16x8*)(kc_ + ct * 1024 + 512);
    }
    // ---- rg0: QK^T -> exp2 -> P ----
    {
      f32x4 st[4];
#pragma unroll
      for (int ct = 0; ct < 4; ++ct) {
        f32x4 z = {0.f, 0.f, 0.f, 0.f};
        z = MFMA16(ka[ct], q0[0], z);
        z = MFMA16(kb2[ct], q1[0], z);
        st[ct] = z;
      }
#pragma unroll
      for (int ct = 0; ct < 4; ++ct) {
        float p0 = EXP2(st[ct][0]);
        float p1 = EXP2(st[ct][1]);
        float p2 = EXP2(st[ct][2]);
        float p3 = EXP2(st[ct][3]);
        l_acc[0] += (p0 + p1) + (p2 + p3);
        uint2 u; u.x = pk2(p0, p1); u.y = pk2(p2, p3);
        *(uint2*)&myp0[ct * 16 + g * 4] = u;
      }
    }
    // ---- rg1: QK^T -> exp2 -> P ----
    {
      f32x4 st[4];
#pragma unroll
      for (int ct = 0; ct < 4; ++ct) {
        f32x4 z = {0.f, 0.f, 0.f, 0.f};
        z = MFMA16(ka[ct], q0[1], z);
        z = MFMA16(kb2[ct], q1[1], z);
        st[ct] = z;
      }
#pragma unroll
      for (int ct = 0; ct < 4; ++ct) {
        float p0 = EXP2(st[ct][0]);
        float p1 = EXP2(st[ct][1]);
        float p2 = EXP2(st[ct][2]);
        float p3 = EXP2(st[ct][3]);
        l_acc[1] += (p0 + p1) + (p2 + p3);
        uint2 u; u.x = pk2(p0, p1); u.y = pk2(p2, p3);
        *(uint2*)&myp1[ct * 16 + g * 4] = u;
      }
    }
    // ---- V frags (shared by both rgs) + PV ----
    const unsigned short* vc_ = vfb + kt * 4096;
    s16x8 va[4], vb2[4];
#pragma unroll
    for (int dt = 0; dt < 4; ++dt) {
      va[dt] = *(const s16x8*)(vc_ + dt * 1024);
      vb2[dt] = *(const s16x8*)(vc_ + dt * 1024 + 512);
    }
    s16x8 pa0 = *(const s16x8*)&myp0[g * 8];
    s16x8 pa1 = *(const s16x8*)&myp0[32 + g * 8];
#pragma unroll
    for (int dt = 0; dt < 4; ++dt) {
      o[0][dt] = MFMA16(pa0, va[dt], o[0][dt]);
      o[0][dt] = MFMA16(pa1, vb2[dt], o[0][dt]);
    }
    s16x8 pb0 = *(const s16x8*)&myp1[g * 8];
    s16x8 pb1 = *(const s16x8*)&myp1[32 + g * 8];
#pragma unroll
    for (int dt = 0; dt < 4; ++dt) {
      o[1][dt] = MFMA16(pb0, va[dt], o[1][dt]);
      o[1][dt] = MFMA16(pb1, vb2[dt], o[1][dt]);
    }
  }

  // row-sums of l (lanes j,j+16,j+32,j+48 share q-row j)
#pragma unroll
  for (int rg = 0; rg < 2; ++rg) {
    l_acc[rg] += __shfl_xor(l_acc[rg], 16);
    l_acc[rg] += __shfl_xor(l_acc[rg], 32);
  }

  __syncthreads();  // all waves done with P; raw becomes comb
#pragma unroll
  for (int rg = 0; rg < 2; ++rg) {
#pragma unroll
    for (int dt = 0; dt < 4; ++dt)
#pragma unroll
      for (int r = 0; r < 4; ++r)
        comb[((size_t)wv * 32 + rg * 16 + g * 4 + r) * 68 + dt * 16 + j] = o[rg][dt][r];
    if (g == 0) lls[wv][rg * 16 + j] = l_acc[rg];
  }
  __syncthreads();

  // merge over the 8 kv chunks (pure sum; shift-0) and normalize
#pragma unroll
  for (int it = 0; it < 4; ++it) {
    const int idx = it * 512 + tid;   // 0..2047
    const int row = idx >> 6;         // 0..31 within block tile
    const int d = idx & 63;
    float s = 0.f, lt = 0.f;
#pragma unroll
    for (int cc = 0; cc < 8; ++cc) {
      s += comb[((size_t)cc * 32 + row) * 68 + d];
      lt += lls[cc][row];
    }
    out[(((size_t)b * 2048) + qt * 32 + row) * 64 + d] = s / lt;
  }
}

extern "C" void kernel_launch(void* const* d_in, const int* in_sizes, int n_in,
                              void* d_out, int out_size, void* d_ws, size_t ws_size,
                              hipStream_t stream) {
  const float* query = (const float*)d_in[0];
  const float* key_  = (const float*)d_in[1];
  const float* value = (const float*)d_in[2];
  const float* Wq = (const float*)d_in[3];
  const float* Wk = (const float*)d_in[4];
  const float* Wv = (const float*)d_in[5];

  unsigned short* qfb = (unsigned short*)d_ws;      // 1M shorts
  unsigned short* kfb = qfb + 1048576u;             // 1M shorts
  unsigned short* vfb = qfb + 2u * 1048576u;        // 1M shorts
  float* outp = (float*)d_out;

  hipLaunchKernelGGL(proj_kernel, dim3(768), dim3(256), 0, stream,
                     query, key_, value, Wq, Wk, Wv, qfb, kfb, vfb);
  hipLaunchKernelGGL(attn_kernel, dim3(512), dim3(512), 0, stream,
                     qfb, kfb, vfb, outp);
}